// Round 2
// baseline (79759.595 us; speedup 1.0000x reference)
//
#include <hip/hip_runtime.h>
#include <math.h>

// Problem constants
#define BB  64
#define TT  512
#define IN  64
#define HH  512
#define ZHH 128
#define NZZ 32
#define NT  1024   // threads per WG = 16 waves; one WG per batch

__device__ __forceinline__ float sigmoidf_(float x) {
    return 1.0f / (1.0f + __expf(-x));
}

__device__ __forceinline__ float dot4(const float4 a, const float4 b) {
    return a.x*b.x + a.y*b.y + a.z*b.z + a.w*b.w;
}

// full 64-lane butterfly reduction
__device__ __forceinline__ float wred(float v) {
    v += __shfl_xor(v, 32, 64);
    v += __shfl_xor(v, 16, 64);
    v += __shfl_xor(v, 8, 64);
    v += __shfl_xor(v, 4, 64);
    v += __shfl_xor(v, 2, 64);
    v += __shfl_xor(v, 1, 64);
    return v;
}

// One workgroup == one batch element. The T=512 recurrence is sequential per
// batch but batches are fully independent -> NO inter-WG sync anywhere.
// All state + intermediates live in LDS (~20 KB). Weights stream from L2
// every step (8 WGs per XCD share the same L2-resident copy).
__global__ __launch_bounds__(NT)
void hypercell_batch(
    const float* __restrict__ xs, const float* __restrict__ cond,
    const float* __restrict__ h_c, const float* __restrict__ h_c_hat,
    const float* __restrict__ x2h_w, const float* __restrict__ x2h_b,
    const float* __restrict__ h2h_w, const float* __restrict__ h2h_b,
    const float* __restrict__ zh_w, const float* __restrict__ zh_b,
    const float* __restrict__ zx_w, const float* __restrict__ zx_b,
    const float* __restrict__ zb_w,
    const float* __restrict__ dh_w, const float* __restrict__ dx_w,
    const float* __restrict__ db_w, const float* __restrict__ db_b,
    const float* __restrict__ wh, const float* __restrict__ wx,
    float* __restrict__ out)
{
    __shared__ float h_s[HH];        // h state
    __shared__ float hhat_s[ZHH];    // hyper state
    __shared__ float x_s[IN];
    __shared__ float cond_s[IN];
    __shared__ float whh_s[3*HH];    // 1536
    __shared__ float wxx_s[3*HH];    // 1536
    __shared__ float ih_s[3*ZHH];    // 384
    __shared__ float hh_s[3*ZHH];    // 384
    __shared__ float z_s[288];       // [kind(3)][l(3)][nz(32)]

    const int b    = blockIdx.x;
    const int tid  = threadIdx.x;
    const int lane = tid & 63;
    const int wv   = tid >> 6;       // wave id 0..15

    // ---- load initial state ----
    if (tid < IN)  cond_s[tid] = cond[(size_t)b*IN + tid];
    if (tid < HH)  h_s[tid]    = h_c[(size_t)b*HH + tid];
    if (tid < ZHH) hhat_s[tid] = h_c_hat[(size_t)b*ZHH + tid];
    __syncthreads();

    for (int t = 0; t < TT; ++t) {
        // stage x_t (consumed after the first sync)
        if (tid < IN) x_s[tid] = xs[((size_t)b*TT + t)*IN + tid];

        // hoisted per-lane fragments of h (K=512 split: lane*4 and 256+lane*4)
        const float4* h4 = (const float4*)h_s;
        const float4 ha = h4[lane];
        const float4 hb = h4[64 + lane];

        // ===== (a) whh[g] = wh[g,:] . h  — wave-per-row, 96 rows/wave =====
        {
            const float* wl = wh + (size_t)(wv*96)*HH + lane*4;
            #pragma unroll 4
            for (int i = 0; i < 96; ++i) {
                float4 wa = *(const float4*)(wl + (size_t)i*HH);
                float4 wb = *(const float4*)(wl + (size_t)i*HH + 256);
                float p = dot4(wa, ha) + dot4(wb, hb);
                p = wred(p);
                if (lane == 0) whh_s[wv*96 + i] = p;
            }
        }

        // ===== (c) ih[j] = [h,cond] . x2h_w[j,:] + b — 24 rows/wave, K=576 =====
        {
            const float cv = cond_s[lane];
            const float* wbase = x2h_w + (size_t)(wv*24)*576;
            #pragma unroll 2
            for (int i = 0; i < 24; ++i) {
                const float* wr = wbase + (size_t)i*576;
                float4 wa = *(const float4*)(wr + lane*4);
                float4 wb = *(const float4*)(wr + 256 + lane*4);
                float  wc = wr[512 + lane];
                float p = dot4(wa, ha) + dot4(wb, hb) + wc*cv;
                p = wred(p);
                if (lane == 0) ih_s[wv*24 + i] = p + x2h_b[wv*24 + i];
            }
        }

        // ===== (d) hh[j] = hhat_old . h2h_w[j,:] + b — 24 rows/wave, K=128 =====
        {
            const float2 hv = ((const float2*)hhat_s)[lane];
            const float* wbase = h2h_w + (size_t)(wv*24)*ZHH;
            #pragma unroll 4
            for (int i = 0; i < 24; ++i) {
                float2 w = *(const float2*)(wbase + (size_t)i*ZHH + lane*2);
                float p = w.x*hv.x + w.y*hv.y;
                p = wred(p);
                if (lane == 0) hh_s[wv*24 + i] = p + h2h_b[wv*24 + i];
            }
        }
        __syncthreads();   // x_s ready; whh/ih/hh complete

        // ===== (b) wxx — thread-per-row, K=64 (rows 0..1535) =====
        {
            const float4* x4 = (const float4*)x_s;
            {
                const float4* wr = (const float4*)(wx + (size_t)tid*IN);
                float acc = 0.f;
                #pragma unroll
                for (int j = 0; j < 16; ++j) acc += dot4(wr[j], x4[j]);
                wxx_s[tid] = acc;
            }
            if (tid < 512) {
                const int r = 1024 + tid;
                const float4* wr = (const float4*)(wx + (size_t)r*IN);
                float acc = 0.f;
                #pragma unroll
                for (int j = 0; j < 16; ++j) acc += dot4(wr[j], x4[j]);
                wxx_s[r] = acc;
            }
        }

        // ===== hyper GRU gates -> hhat_new (in place) =====
        if (tid < ZHH) {
            const int j = tid;
            float r = sigmoidf_(ih_s[j]       + hh_s[j]);
            float g = sigmoidf_(ih_s[ZHH+j]   + hh_s[ZHH+j]);
            float n = tanhf   (ih_s[2*ZHH+j] + r*hh_s[2*ZHH+j]);
            float hn = n + g*(hhat_s[j] - n);
            hhat_s[j] = hn;
            if (t == TT-1)
                out[(size_t)BB*TT*HH + (size_t)BB*HH + (size_t)b*ZHH + j] = hn;
        }
        __syncthreads();   // hhat_new + wxx ready

        // ===== (e) z[R] = hhat_new . zw[R,:] + b — 18 rows/wave, K=128 =====
        {
            const float2 hv = ((const float2*)hhat_s)[lane];
            #pragma unroll 2
            for (int i = 0; i < 18; ++i) {
                const int R = wv*18 + i;          // 0..287
                const int kind = R / 96, r96 = R % 96;
                const float* wsrc = (kind == 0) ? zh_w : ((kind == 1) ? zx_w : zb_w);
                float2 w = *(const float2*)(wsrc + (size_t)r96*ZHH + lane*2);
                float p = wred(w.x*hv.x + w.y*hv.y);
                if (lane == 0) {
                    float bias = (kind == 0) ? zh_b[r96] : ((kind == 1) ? zx_b[r96] : 0.f);
                    z_s[R] = p + bias;
                }
            }
        }
        __syncthreads();   // z ready

        // ===== (f) d scales (K=32) + main gates -> h_new — thread-per-h =====
        if (tid < HH) {
            const int h = tid;
            const float* dsrc[3] = { dh_w, dx_w, db_w };
            float dv[3][3];
            #pragma unroll
            for (int kind = 0; kind < 3; ++kind) {
                #pragma unroll
                for (int l = 0; l < 3; ++l) {
                    const float4* wr = (const float4*)(dsrc[kind] + ((size_t)l*HH + h)*NZZ);
                    const float4* zp = (const float4*)&z_s[kind*96 + l*32];
                    float acc = 0.f;
                    #pragma unroll
                    for (int j = 0; j < 8; ++j) acc += dot4(wr[j], zp[j]);
                    dv[kind][l] = acc;
                }
            }
            const float whh0 = whh_s[h], whh1 = whh_s[HH+h], whh2 = whh_s[2*HH+h];
            const float wxx0 = wxx_s[h], wxx1 = wxx_s[HH+h], wxx2 = wxx_s[2*HH+h];
            const float db0 = dv[2][0] + db_b[h];
            const float db1 = dv[2][1] + db_b[HH + h];
            const float db2 = dv[2][2] + db_b[2*HH + h];
            float r0 = sigmoidf_(dv[0][0]*whh0 + dv[1][0]*wxx0 + db0);
            float g0 = sigmoidf_(dv[0][1]*whh1 + dv[1][1]*wxx1 + db1);
            float n0 = tanhf  (r0*dv[0][2]*whh2 + dv[1][2]*wxx2 + db2);
            float hold = h_s[h];
            float hnew = n0 + g0*(hold - n0);
            h_s[h] = hnew;
            out[((size_t)b*TT + t)*HH + h] = hnew;
            if (t == TT-1) out[(size_t)BB*TT*HH + (size_t)b*HH + h] = hnew;
        }
        __syncthreads();   // h_new published to LDS for next step
    }
}

extern "C" void kernel_launch(void* const* d_in, const int* in_sizes, int n_in,
                              void* d_out, int out_size, void* d_ws, size_t ws_size,
                              hipStream_t stream) {
    const float* xs      = (const float*)d_in[0];
    const float* cond    = (const float*)d_in[1];
    const float* h_c     = (const float*)d_in[2];
    const float* h_c_hat = (const float*)d_in[3];
    const float* x2h_w   = (const float*)d_in[4];
    const float* x2h_b   = (const float*)d_in[5];
    const float* h2h_w   = (const float*)d_in[6];
    const float* h2h_b   = (const float*)d_in[7];
    const float* zh_w    = (const float*)d_in[8];
    const float* zh_b    = (const float*)d_in[9];
    const float* zx_w    = (const float*)d_in[10];
    const float* zx_b    = (const float*)d_in[11];
    const float* zb_w    = (const float*)d_in[12];
    const float* dh_w    = (const float*)d_in[13];
    const float* dx_w    = (const float*)d_in[14];
    const float* db_w    = (const float*)d_in[15];
    const float* db_b    = (const float*)d_in[16];
    const float* wh      = (const float*)d_in[17];
    const float* wx      = (const float*)d_in[18];
    float* out = (float*)d_out;

    hipLaunchKernelGGL(hypercell_batch, dim3(BB), dim3(NT), 0, stream,
                       xs, cond, h_c, h_c_hat, x2h_w, x2h_b, h2h_w, h2h_b,
                       zh_w, zh_b, zx_w, zx_b, zb_w, dh_w, dx_w, db_w, db_b,
                       wh, wx, out);
}

// Round 3
// 58639.014 us; speedup vs baseline: 1.3602x; 1.3602x over previous
//
#include <hip/hip_runtime.h>
#include <math.h>

// Problem constants
#define BB  64
#define TT  512
#define IN  64
#define HH  512
#define ZHH 128
#define NZZ 32
#define NT  1024   // 16 waves; one WG per batch

// bf16 weight buffer layout in d_ws (element offsets, unsigned short)
#define U_WH   0          // [1536][512]
#define U_X2H  786432     // [384][576]  (cols 512..575 = cond part)
#define U_H2H  1007616    // [384][128]
#define U_WX   1056768    // [1536][64]
#define U_Z    1155072    // [288][128]  (zh||zx||zb)
#define U_D    1191936    // [3 kind][3 l][512 h][32 nz] (dh||dx||db)
#define U_END  1339392

typedef __attribute__((ext_vector_type(4))) float floatx4;
typedef __attribute__((ext_vector_type(8))) short shortx8;

__device__ __forceinline__ float sigmoidf_(float x) {
    return 1.0f / (1.0f + __expf(-x));
}

__device__ __forceinline__ float bflo(unsigned u) { return __uint_as_float(u << 16); }
__device__ __forceinline__ float bfhi(unsigned u) { return __uint_as_float(u & 0xffff0000u); }

__device__ __forceinline__ unsigned short f2bf(float f) {
    unsigned u = __float_as_uint(f);
    return (unsigned short)((u + 0x7fffu + ((u >> 16) & 1u)) >> 16);
}

__device__ __forceinline__ float wred(float v) {
    v += __shfl_xor(v, 32, 64);
    v += __shfl_xor(v, 16, 64);
    v += __shfl_xor(v, 8, 64);
    v += __shfl_xor(v, 4, 64);
    v += __shfl_xor(v, 2, 64);
    v += __shfl_xor(v, 1, 64);
    return v;
}

// acc += dot(8 bf16 packed in uint4, 8 floats in two float4)
__device__ __forceinline__ float dotbf8(uint4 U, float4 a, float4 b) {
    return bflo(U.x)*a.x + bfhi(U.x)*a.y + bflo(U.y)*a.z + bfhi(U.y)*a.w
         + bflo(U.z)*b.x + bfhi(U.z)*b.y + bflo(U.w)*b.z + bfhi(U.w)*b.w;
}

// ---------- pre-pass: fp32 -> bf16 (RNE) into ws ----------
__global__ __launch_bounds__(256)
void conv_bf16(const float* __restrict__ wh, const float* __restrict__ x2h,
               const float* __restrict__ h2h, const float* __restrict__ wx,
               const float* __restrict__ zh, const float* __restrict__ zx,
               const float* __restrict__ zb, const float* __restrict__ dh,
               const float* __restrict__ dx, const float* __restrict__ db,
               unsigned short* __restrict__ o)
{
    int i = blockIdx.x * 256 + threadIdx.x;
    float v;
    if      (i < 786432)  v = wh[i];
    else if (i < 1007616) v = x2h[i - 786432];
    else if (i < 1056768) v = h2h[i - 1007616];
    else if (i < 1155072) v = wx[i - 1056768];
    else if (i < 1167360) v = zh[i - 1155072];
    else if (i < 1179648) v = zx[i - 1167360];
    else if (i < 1191936) v = zb[i - 1179648];
    else if (i < 1241088) v = dh[i - 1191936];
    else if (i < 1290240) v = dx[i - 1241088];
    else if (i < U_END)   v = db[i - 1290240];
    else return;
    o[i] = f2bf(v);
}

// ---------- main kernel: one WG per batch, bf16 weights, MFMA for K=512 ----------
__global__ __launch_bounds__(NT)
void hypercell_mfma(
    const float* __restrict__ xs, const float* __restrict__ cond,
    const float* __restrict__ h_c, const float* __restrict__ h_c_hat,
    const float* __restrict__ x2h_b, const float* __restrict__ h2h_b,
    const float* __restrict__ zh_b, const float* __restrict__ zx_b,
    const float* __restrict__ db_b,
    const unsigned short* __restrict__ wbf,
    float* __restrict__ out)
{
    __shared__ float h_s[HH];
    __shared__ float x_s[IN];
    __shared__ float hhat_s[ZHH];
    __shared__ float whh_s[3*HH];
    __shared__ float wxx_s[3*HH];
    __shared__ float ih_s[3*ZHH];
    __shared__ float hh_s[3*ZHH];
    __shared__ float ihc_s[3*ZHH];   // time-invariant cond part of ih (+bias)
    __shared__ float z_s[288];
    __shared__ __align__(16) unsigned short hbf_s[HH];

    const int b    = blockIdx.x;
    const int tid  = threadIdx.x;
    const int lane = tid & 63;
    const int wv   = tid >> 6;       // 0..15
    const int quad = lane >> 4;      // 0..3
    const int l16  = lane & 15;

    // ---- init state; stage cond into x_s for the ihc precompute ----
    if (tid < IN) x_s[tid] = cond[(size_t)b*IN + tid];
    if (tid < HH) { float v = h_c[(size_t)b*HH + tid]; h_s[tid] = v; hbf_s[tid] = f2bf(v); }
    if (tid < ZHH) hhat_s[tid] = h_c_hat[(size_t)b*ZHH + tid];
    __syncthreads();

    // ihc[r] = cond . x2h_w[r,512:576] + x2h_b[r]   (time-invariant)
    if (tid < 384) {
        const uint4* w4 = (const uint4*)(wbf + U_X2H + (size_t)tid*576 + 512);
        const float4* c4 = (const float4*)x_s;
        float acc = x2h_b[tid];
        #pragma unroll
        for (int j = 0; j < 8; ++j)
            acc += dotbf8(w4[j], c4[2*j], c4[2*j+1]);
        ihc_s[tid] = acc;
    }
    __syncthreads();

    for (int t = 0; t < TT; ++t) {
        if (tid < IN) x_s[tid] = xs[((size_t)b*TT + t)*IN + tid];
        __syncthreads();   // x_s staged; hbf_s/h_s from prev step visible

        // ===== MFMA: whh (nblocks 0..95) + ih h-part (nblocks 96..119) =====
        // D[m][n] = sum_k A[m][k]*B[k][n]; A = h (replicated over m),
        // B columns n = weight rows g. A/B frag: lane&15 = m/n, k = quad*8+j.
        {
            floatx4 acc[8];
            #pragma unroll
            for (int i = 0; i < 8; ++i) acc[i] = (floatx4){0.f, 0.f, 0.f, 0.f};
            for (int kh = 0; kh < 2; ++kh) {
                shortx8 aF[8];
                #pragma unroll
                for (int kb = 0; kb < 8; ++kb)
                    aF[kb] = *(const shortx8*)&hbf_s[kh*256 + kb*32 + quad*8];
                #pragma unroll
                for (int i = 0; i < 8; ++i) {
                    const int nb = wv + 16*i;
                    if (nb < 120) {
                        const unsigned short* wp;
                        if (nb < 96)
                            wp = wbf + U_WH + ((size_t)(nb*16 + l16))*512 + kh*256 + quad*8;
                        else
                            wp = wbf + U_X2H + ((size_t)((nb-96)*16 + l16))*576 + kh*256 + quad*8;
                        floatx4 a = acc[i];
                        #pragma unroll
                        for (int kb = 0; kb < 8; ++kb) {
                            shortx8 bF = *(const shortx8*)(wp + kb*32);
                            a = __builtin_amdgcn_mfma_f32_16x16x32_bf16(aF[kb], bF, a, 0, 0, 0);
                        }
                        acc[i] = a;
                    }
                }
            }
            // all D rows identical; take row 0 (reg 0 of lanes 0..15)
            #pragma unroll
            for (int i = 0; i < 8; ++i) {
                const int nb = wv + 16*i;
                if (nb < 120 && lane < 16) {
                    float v = acc[i][0];
                    if (nb < 96) whh_s[nb*16 + lane] = v;
                    else { int r = (nb-96)*16 + lane; ih_s[r] = v + ihc_s[r]; }
                }
            }
        }

        // ===== vector hh: 24 rows/wave, K=128 (old hhat) =====
        {
            float2 hv = *(const float2*)&hhat_s[lane*2];
            #pragma unroll 4
            for (int i = 0; i < 24; ++i) {
                int r = wv*24 + i;
                unsigned u = *(const unsigned*)(wbf + U_H2H + (size_t)r*128 + lane*2);
                float p = wred(bflo(u)*hv.x + bfhi(u)*hv.y);
                if (lane == 0) hh_s[r] = p + h2h_b[r];
            }
        }

        // ===== vector wxx: thread-per-row, K=64 =====
        {
            const float4* x4 = (const float4*)x_s;
            {
                const uint4* w4 = (const uint4*)(wbf + U_WX + (size_t)tid*64);
                float acc = 0.f;
                #pragma unroll
                for (int j = 0; j < 8; ++j)
                    acc += dotbf8(w4[j], x4[2*j], x4[2*j+1]);
                wxx_s[tid] = acc;
            }
            if (tid < 512) {
                const int r = 1024 + tid;
                const uint4* w4 = (const uint4*)(wbf + U_WX + (size_t)r*64);
                float acc = 0.f;
                #pragma unroll
                for (int j = 0; j < 8; ++j)
                    acc += dotbf8(w4[j], x4[2*j], x4[2*j+1]);
                wxx_s[r] = acc;
            }
        }
        __syncthreads();   // ih/hh/whh/wxx complete

        // ===== hyper GRU gates -> hhat_new =====
        if (tid < ZHH) {
            const int j = tid;
            float r = sigmoidf_(ih_s[j] + hh_s[j]);
            float g = sigmoidf_(ih_s[ZHH+j] + hh_s[ZHH+j]);
            float n = tanhf(ih_s[2*ZHH+j] + r*hh_s[2*ZHH+j]);
            float hn = n + g*(hhat_s[j] - n);
            hhat_s[j] = hn;
            if (t == TT-1)
                out[(size_t)BB*TT*HH + (size_t)BB*HH + (size_t)b*ZHH + j] = hn;
        }
        __syncthreads();   // hhat_new visible

        // ===== z: 18 rows/wave, K=128 =====
        {
            float2 hv = *(const float2*)&hhat_s[lane*2];
            #pragma unroll 2
            for (int i = 0; i < 18; ++i) {
                int R = wv*18 + i;
                unsigned u = *(const unsigned*)(wbf + U_Z + (size_t)R*128 + lane*2);
                float p = wred(bflo(u)*hv.x + bfhi(u)*hv.y);
                if (lane == 0) {
                    float bias = (R < 96) ? zh_b[R] : ((R < 192) ? zx_b[R-96] : 0.f);
                    z_s[R] = p + bias;
                }
            }
        }
        __syncthreads();   // z ready

        // ===== d scales (9 dots K=32) + main gates -> h_new =====
        if (tid < HH) {
            const int h = tid;
            float dv[3][3];
            #pragma unroll
            for (int kind = 0; kind < 3; ++kind) {
                #pragma unroll
                for (int l = 0; l < 3; ++l) {
                    const uint4* w4 = (const uint4*)(wbf + U_D + ((size_t)((kind*3+l)*HH + h))*NZZ);
                    const float4* z4 = (const float4*)&z_s[kind*96 + l*32];
                    float acc = 0.f;
                    #pragma unroll
                    for (int j = 0; j < 4; ++j)
                        acc += dotbf8(w4[j], z4[2*j], z4[2*j+1]);
                    dv[kind][l] = acc;
                }
            }
            const float whh0 = whh_s[h], whh1 = whh_s[HH+h], whh2 = whh_s[2*HH+h];
            const float wxx0 = wxx_s[h], wxx1 = wxx_s[HH+h], wxx2 = wxx_s[2*HH+h];
            const float db0 = dv[2][0] + db_b[h];
            const float db1 = dv[2][1] + db_b[HH + h];
            const float db2 = dv[2][2] + db_b[2*HH + h];
            float r0 = sigmoidf_(dv[0][0]*whh0 + dv[1][0]*wxx0 + db0);
            float g0 = sigmoidf_(dv[0][1]*whh1 + dv[1][1]*wxx1 + db1);
            float n0 = tanhf  (r0*dv[0][2]*whh2 + dv[1][2]*wxx2 + db2);
            float hold = h_s[h];
            float hnew = n0 + g0*(hold - n0);
            h_s[h] = hnew;
            hbf_s[h] = f2bf(hnew);
            out[((size_t)b*TT + t)*HH + h] = hnew;
            if (t == TT-1) out[(size_t)BB*TT*HH + (size_t)b*HH + h] = hnew;
        }
        __syncthreads();   // h_s/hbf_s published; whh_s safe to overwrite next step
    }
}

// ---------- fp32 fallback (R2 kernel, used only if ws too small) ----------
__device__ __forceinline__ float dot4_(const float4 a, const float4 b) {
    return a.x*b.x + a.y*b.y + a.z*b.z + a.w*b.w;
}

__global__ __launch_bounds__(NT)
void hypercell_batch(
    const float* __restrict__ xs, const float* __restrict__ cond,
    const float* __restrict__ h_c, const float* __restrict__ h_c_hat,
    const float* __restrict__ x2h_w, const float* __restrict__ x2h_b,
    const float* __restrict__ h2h_w, const float* __restrict__ h2h_b,
    const float* __restrict__ zh_w, const float* __restrict__ zh_b,
    const float* __restrict__ zx_w, const float* __restrict__ zx_b,
    const float* __restrict__ zb_w,
    const float* __restrict__ dh_w, const float* __restrict__ dx_w,
    const float* __restrict__ db_w, const float* __restrict__ db_b,
    const float* __restrict__ wh, const float* __restrict__ wx,
    float* __restrict__ out)
{
    __shared__ float h_s[HH];
    __shared__ float hhat_s[ZHH];
    __shared__ float x_s[IN];
    __shared__ float cond_s[IN];
    __shared__ float whh_s[3*HH];
    __shared__ float wxx_s[3*HH];
    __shared__ float ih_s[3*ZHH];
    __shared__ float hh_s[3*ZHH];
    __shared__ float z_s[288];

    const int b    = blockIdx.x;
    const int tid  = threadIdx.x;
    const int lane = tid & 63;
    const int wv   = tid >> 6;

    if (tid < IN)  cond_s[tid] = cond[(size_t)b*IN + tid];
    if (tid < HH)  h_s[tid]    = h_c[(size_t)b*HH + tid];
    if (tid < ZHH) hhat_s[tid] = h_c_hat[(size_t)b*ZHH + tid];
    __syncthreads();

    for (int t = 0; t < TT; ++t) {
        if (tid < IN) x_s[tid] = xs[((size_t)b*TT + t)*IN + tid];
        const float4* h4 = (const float4*)h_s;
        const float4 ha = h4[lane];
        const float4 hb = h4[64 + lane];
        {
            const float* wl = wh + (size_t)(wv*96)*HH + lane*4;
            #pragma unroll 4
            for (int i = 0; i < 96; ++i) {
                float4 wa = *(const float4*)(wl + (size_t)i*HH);
                float4 wb = *(const float4*)(wl + (size_t)i*HH + 256);
                float p = wred(dot4_(wa, ha) + dot4_(wb, hb));
                if (lane == 0) whh_s[wv*96 + i] = p;
            }
        }
        {
            const float cv = cond_s[lane];
            const float* wbase = x2h_w + (size_t)(wv*24)*576;
            #pragma unroll 2
            for (int i = 0; i < 24; ++i) {
                const float* wr = wbase + (size_t)i*576;
                float4 wa = *(const float4*)(wr + lane*4);
                float4 wb = *(const float4*)(wr + 256 + lane*4);
                float  wc = wr[512 + lane];
                float p = wred(dot4_(wa, ha) + dot4_(wb, hb) + wc*cv);
                if (lane == 0) ih_s[wv*24 + i] = p + x2h_b[wv*24 + i];
            }
        }
        {
            const float2 hv = ((const float2*)hhat_s)[lane];
            const float* wbase = h2h_w + (size_t)(wv*24)*ZHH;
            #pragma unroll 4
            for (int i = 0; i < 24; ++i) {
                float2 w = *(const float2*)(wbase + (size_t)i*ZHH + lane*2);
                float p = wred(w.x*hv.x + w.y*hv.y);
                if (lane == 0) hh_s[wv*24 + i] = p + h2h_b[wv*24 + i];
            }
        }
        __syncthreads();
        {
            const float4* x4 = (const float4*)x_s;
            {
                const float4* wr = (const float4*)(wx + (size_t)tid*IN);
                float acc = 0.f;
                #pragma unroll
                for (int j = 0; j < 16; ++j) acc += dot4_(wr[j], x4[j]);
                wxx_s[tid] = acc;
            }
            if (tid < 512) {
                const int r = 1024 + tid;
                const float4* wr = (const float4*)(wx + (size_t)r*IN);
                float acc = 0.f;
                #pragma unroll
                for (int j = 0; j < 16; ++j) acc += dot4_(wr[j], x4[j]);
                wxx_s[r] = acc;
            }
        }
        if (tid < ZHH) {
            const int j = tid;
            float r = sigmoidf_(ih_s[j] + hh_s[j]);
            float g = sigmoidf_(ih_s[ZHH+j] + hh_s[ZHH+j]);
            float n = tanhf(ih_s[2*ZHH+j] + r*hh_s[2*ZHH+j]);
            float hn = n + g*(hhat_s[j] - n);
            hhat_s[j] = hn;
            if (t == TT-1)
                out[(size_t)BB*TT*HH + (size_t)BB*HH + (size_t)b*ZHH + j] = hn;
        }
        __syncthreads();
        {
            const float2 hv = ((const float2*)hhat_s)[lane];
            #pragma unroll 2
            for (int i = 0; i < 18; ++i) {
                const int R = wv*18 + i;
                const int kind = R / 96, r96 = R % 96;
                const float* wsrc = (kind == 0) ? zh_w : ((kind == 1) ? zx_w : zb_w);
                float2 w = *(const float2*)(wsrc + (size_t)r96*ZHH + lane*2);
                float p = wred(w.x*hv.x + w.y*hv.y);
                if (lane == 0) {
                    float bias = (kind == 0) ? zh_b[r96] : ((kind == 1) ? zx_b[r96] : 0.f);
                    z_s[R] = p + bias;
                }
            }
        }
        __syncthreads();
        if (tid < HH) {
            const int h = tid;
            const float* dsrc[3] = { dh_w, dx_w, db_w };
            float dv[3][3];
            #pragma unroll
            for (int kind = 0; kind < 3; ++kind) {
                #pragma unroll
                for (int l = 0; l < 3; ++l) {
                    const float4* wr = (const float4*)(dsrc[kind] + ((size_t)l*HH + h)*NZZ);
                    const float4* zp = (const float4*)&z_s[kind*96 + l*32];
                    float acc = 0.f;
                    #pragma unroll
                    for (int j = 0; j < 8; ++j) acc += dot4_(wr[j], zp[j]);
                    dv[kind][l] = acc;
                }
            }
            const float whh0 = whh_s[h], whh1 = whh_s[HH+h], whh2 = whh_s[2*HH+h];
            const float wxx0 = wxx_s[h], wxx1 = wxx_s[HH+h], wxx2 = wxx_s[2*HH+h];
            const float db0 = dv[2][0] + db_b[h];
            const float db1 = dv[2][1] + db_b[HH + h];
            const float db2 = dv[2][2] + db_b[2*HH + h];
            float r0 = sigmoidf_(dv[0][0]*whh0 + dv[1][0]*wxx0 + db0);
            float g0 = sigmoidf_(dv[0][1]*whh1 + dv[1][1]*wxx1 + db1);
            float n0 = tanhf  (r0*dv[0][2]*whh2 + dv[1][2]*wxx2 + db2);
            float hold = h_s[h];
            float hnew = n0 + g0*(hold - n0);
            h_s[h] = hnew;
            out[((size_t)b*TT + t)*HH + h] = hnew;
            if (t == TT-1) out[(size_t)BB*TT*HH + (size_t)b*HH + h] = hnew;
        }
        __syncthreads();
    }
}

extern "C" void kernel_launch(void* const* d_in, const int* in_sizes, int n_in,
                              void* d_out, int out_size, void* d_ws, size_t ws_size,
                              hipStream_t stream) {
    const float* xs      = (const float*)d_in[0];
    const float* cond    = (const float*)d_in[1];
    const float* h_c     = (const float*)d_in[2];
    const float* h_c_hat = (const float*)d_in[3];
    const float* x2h_w   = (const float*)d_in[4];
    const float* x2h_b   = (const float*)d_in[5];
    const float* h2h_w   = (const float*)d_in[6];
    const float* h2h_b   = (const float*)d_in[7];
    const float* zh_w    = (const float*)d_in[8];
    const float* zh_b    = (const float*)d_in[9];
    const float* zx_w    = (const float*)d_in[10];
    const float* zx_b    = (const float*)d_in[11];
    const float* zb_w    = (const float*)d_in[12];
    const float* dh_w    = (const float*)d_in[13];
    const float* dx_w    = (const float*)d_in[14];
    const float* db_w    = (const float*)d_in[15];
    const float* db_b    = (const float*)d_in[16];
    const float* wh      = (const float*)d_in[17];
    const float* wx      = (const float*)d_in[18];
    float* out = (float*)d_out;

    if (ws_size >= (size_t)U_END * sizeof(unsigned short)) {
        unsigned short* wbf = (unsigned short*)d_ws;
        hipLaunchKernelGGL(conv_bf16, dim3((U_END + 255)/256), dim3(256), 0, stream,
                           wh, x2h_w, h2h_w, wx, zh_w, zx_w, zb_w, dh_w, dx_w, db_w, wbf);
        hipLaunchKernelGGL(hypercell_mfma, dim3(BB), dim3(NT), 0, stream,
                           xs, cond, h_c, h_c_hat, x2h_b, h2h_b, zh_b, zx_b, db_b,
                           wbf, out);
    } else {
        hipLaunchKernelGGL(hypercell_batch, dim3(BB), dim3(NT), 0, stream,
                           xs, cond, h_c, h_c_hat, x2h_w, x2h_b, h2h_w, h2h_b,
                           zh_w, zh_b, zx_w, zx_b, zb_w, dh_w, dx_w, db_w, db_b,
                           wh, wx, out);
    }
}